// Round 9
// baseline (24487.875 us; speedup 1.0000x reference)
//
#include <hip/hip_runtime.h>

typedef __bf16 bf16_t;
typedef __bf16 bf16x8 __attribute__((ext_vector_type(8)));
typedef float  f32x4  __attribute__((ext_vector_type(4)));

#define DEV __device__ __forceinline__

constexpr int Bn = 256;
constexpr int Ln = 120;
constexpr int Dn = 192;
constexpr int Zn = 512;
constexpr int Hn = 1024;          // H = 2*Z
constexpr int KE = Zn + Hn;       // 1536: encoder lstm K  (x | h)
constexpr int KD = Zn + Dn + Hn;  // 1728: decoder lstm K  (xz | pose | h)
constexpr int CATD = Zn + Dn;     // 704:  decoder non-recurrent input width
constexpr int NEPS = Bn * Zn;     // 131072 gaussians

DEV f32x4 mfma16(bf16x8 a, bf16x8 b, f32x4 c) {
  return __builtin_amdgcn_mfma_f32_16x16x32_bf16(a, b, c, 0, 0, 0);
}
DEV bf16x8 ldb8(const bf16_t* p) { return *reinterpret_cast<const bf16x8*>(p); }
DEV float sigf(float x) { return 1.f / (1.f + expf(-x)); }

// ---------------- prep kernels ----------------
__global__ void k_cast(const float* __restrict__ s, bf16_t* __restrict__ d, int n) {
  for (int i = blockIdx.x * blockDim.x + threadIdx.x; i < n; i += gridDim.x * blockDim.x)
    d[i] = (bf16_t)s[i];
}

__global__ void k_pack2(const float* __restrict__ s1, int k1,
                        const float* __restrict__ s2, int k2,
                        bf16_t* __restrict__ d, long n) {
  int K = k1 + k2;
  for (long i = blockIdx.x * blockDim.x + threadIdx.x; i < n;
       i += (long)gridDim.x * blockDim.x) {
    int r = (int)(i / K), k = (int)(i % K);
    float v = (k < k1) ? s1[(long)r * k1 + k] : s2[(long)r * k2 + (k - k1)];
    d[i] = (bf16_t)v;
  }
}

__global__ void k_addbias(const float* __restrict__ a, const float* __restrict__ b,
                          float* __restrict__ d, int n) {
  int i = blockIdx.x * blockDim.x + threadIdx.x;
  if (i < n) d[i] = a[i] + b[i];
}

// ---------------- layernorm over (L,D) per sample + x passthrough ----------------
__global__ void k_layernorm(const float* __restrict__ x, const float* __restrict__ w,
                            const float* __restrict__ bsh, float* __restrict__ out0,
                            bf16_t* __restrict__ xn) {
  const int n = Ln * Dn;  // 23040
  int b = blockIdx.x;
  const float* xb = x + (long)b * n;
  float s = 0.f, s2 = 0.f;
  for (int i = threadIdx.x; i < n; i += 256) { float v = xb[i]; s += v; s2 += v * v; }
  for (int off = 32; off; off >>= 1) { s += __shfl_down(s, off); s2 += __shfl_down(s2, off); }
  __shared__ float sh[8];
  int wave = threadIdx.x >> 6, lane = threadIdx.x & 63;
  if (lane == 0) { sh[wave] = s; sh[4 + wave] = s2; }
  __syncthreads();
  if (threadIdx.x == 0) {
    float S = sh[0] + sh[1] + sh[2] + sh[3];
    float S2 = sh[4] + sh[5] + sh[6] + sh[7];
    float m = S / n;
    float var = fmaxf(S2 / n - m * m, 0.f);
    sh[0] = m; sh[1] = rsqrtf(var + 1e-5f);
  }
  __syncthreads();
  float m = sh[0], inv = sh[1];
  for (int i = threadIdx.x; i < n; i += 256) {
    float v = xb[i];
    out0[(long)b * n + i] = v;
    xn[(long)b * n + i] = (bf16_t)((v - m) * inv * w[i] + bsh[i]);
  }
}

// ---------------- generic bf16 MFMA GEMM: out = act(A @ W^T + bias) ----------------
template <int ACT, bool XSPERM>
__global__ __launch_bounds__(256) void k_gemm(
    const bf16_t* __restrict__ A, int lda,
    const bf16_t* __restrict__ W, int ldw,
    const float* __restrict__ bias,
    float* __restrict__ outF, long ldoF,
    bf16_t* __restrict__ outB, int ldoB,
    int K) {
  int lane = threadIdx.x & 63, wave = threadIdx.x >> 6;
  int l15 = lane & 15, q = lane >> 4;
  int m0 = blockIdx.x * 64 + (wave >> 1) * 32;
  int n0 = blockIdx.y * 64 + (wave & 1) * 32;
  f32x4 acc00 = {}, acc01 = {}, acc10 = {}, acc11 = {};
  const bf16_t* Ap = A + (long)(m0 + l15) * lda + q * 8;
  const bf16_t* Wp = W + (long)(n0 + l15) * ldw + q * 8;
  long a16 = (long)16 * lda, w16 = (long)16 * ldw;
  for (int k0 = 0; k0 < K; k0 += 32) {
    bf16x8 a0 = ldb8(Ap + k0);
    bf16x8 a1 = ldb8(Ap + a16 + k0);
    bf16x8 b0 = ldb8(Wp + k0);
    bf16x8 b1 = ldb8(Wp + w16 + k0);
    acc00 = mfma16(a0, b0, acc00);
    acc01 = mfma16(a0, b1, acc01);
    acc10 = mfma16(a1, b0, acc10);
    acc11 = mfma16(a1, b1, acc11);
  }
#pragma unroll
  for (int mi = 0; mi < 2; ++mi)
#pragma unroll
    for (int ni = 0; ni < 2; ++ni) {
      f32x4 acc = (mi == 0) ? (ni == 0 ? acc00 : acc01) : (ni == 0 ? acc10 : acc11);
#pragma unroll
      for (int r = 0; r < 4; ++r) {
        int m = m0 + mi * 16 + q * 4 + r;
        int nn = n0 + ni * 16 + l15;
        float v = acc[r] + bias[nn];
        if (ACT == 1) v = fmaxf(v, 0.f);
        if (outF) outF[(long)m * ldoF + nn] = v;
        if (outB) {
          long row = XSPERM ? ((long)(m % Ln) * Bn + m / Ln) : m;
          outB[row * (long)ldoB + nn] = (bf16_t)v;
        }
      }
    }
}

// ---------------- fused encoder BiLSTM step ----------------
__global__ __launch_bounds__(256) void k_enc_step(
    const bf16_t* __restrict__ xs, int t,
    const bf16_t* __restrict__ Wf, const bf16_t* __restrict__ Wb,
    const float* __restrict__ biasf, const float* __restrict__ biasb,
    const int* __restrict__ lens,
    const bf16_t* __restrict__ hf_in, bf16_t* __restrict__ hf_out,
    const bf16_t* __restrict__ hb_in, bf16_t* __restrict__ hb_out,
    float* __restrict__ cf, float* __restrict__ cb,
    float* __restrict__ pooled) {
  int dir = blockIdx.z;
  const bf16_t* W = dir ? Wb : Wf;
  const float* bias = dir ? biasb : biasf;
  const bf16_t* h_in = dir ? hb_in : hf_in;
  bf16_t* h_out = dir ? hb_out : hf_out;
  float* c = dir ? cb : cf;
  int tt = dir ? (Ln - 1 - t) : t;
  const bf16_t* xt = xs + (long)tt * Bn * Zn;

  int lane = threadIdx.x & 63, wave = threadIdx.x >> 6;
  int l15 = lane & 15, q = lane >> 4;
  int m0 = blockIdx.x * 32 + (wave >> 1) * 16;
  int n0 = blockIdx.y * 64 + (wave & 1) * 32;

  f32x4 acc[4][2] = {};
  int mrow = m0 + l15;
  const bf16_t* xrow = xt + (long)mrow * Zn + q * 8;
  const bf16_t* hrow = h_in + (long)mrow * Hn + q * 8;
  const bf16_t* wbase = W + (long)(n0 + l15) * KE + q * 8;

  for (int k0 = 0; k0 < KE; k0 += 32) {
    bf16x8 a = (k0 < Zn) ? ldb8(xrow + k0) : ldb8(hrow + (k0 - Zn));
#pragma unroll
    for (int g = 0; g < 4; ++g) {
      const bf16_t* bp = wbase + (long)g * Hn * KE + k0;
      bf16x8 b0 = ldb8(bp);
      bf16x8 b1 = ldb8(bp + (long)16 * KE);
      acc[g][0] = mfma16(a, b0, acc[g][0]);
      acc[g][1] = mfma16(a, b1, acc[g][1]);
    }
  }
#pragma unroll
  for (int s = 0; s < 2; ++s) {
    int j = n0 + s * 16 + l15;
#pragma unroll
    for (int r = 0; r < 4; ++r) {
      int m = m0 + q * 4 + r;
      float Gi = acc[0][s][r] + bias[j];
      float Gf = acc[1][s][r] + bias[Hn + j];
      float Gg = acc[2][s][r] + bias[2 * Hn + j];
      float Go = acc[3][s][r] + bias[3 * Hn + j];
      float ig = sigf(Gi), fg = sigf(Gf);
      float gg = tanhf(Gg), og = sigf(Go);
      long idx = (long)m * Hn + j;
      float cp = c[idx];
      float cn = fg * cp + ig * gg;
      float hn = og * tanhf(cn);
      bool act = tt < lens[m];
      c[idx] = act ? cn : cp;
      float hw = act ? hn : (float)h_in[idx];
      h_out[idx] = (bf16_t)hw;
      pooled[(long)m * (2 * Hn) + dir * Hn + j] += act ? hn : 0.f;
    }
  }
}

// ---------------- fused decoder LSTM step ----------------
__global__ __launch_bounds__(256) void k_dec_step(
    const bf16_t* __restrict__ inp,
    const bf16_t* __restrict__ h_in, bf16_t* __restrict__ h_out,
    const bf16_t* __restrict__ W, const float* __restrict__ bias,
    float* __restrict__ c) {
  int lane = threadIdx.x & 63, wave = threadIdx.x >> 6;
  int l15 = lane & 15, q = lane >> 4;
  int m0 = blockIdx.x * 32 + (wave >> 1) * 16;
  int n0 = blockIdx.y * 64 + (wave & 1) * 32;

  f32x4 acc[4][2] = {};
  int mrow = m0 + l15;
  const bf16_t* irow = inp + (long)mrow * CATD + q * 8;
  const bf16_t* hrow = h_in + (long)mrow * Hn + q * 8;
  const bf16_t* wbase = W + (long)(n0 + l15) * KD + q * 8;

  for (int k0 = 0; k0 < KD; k0 += 32) {
    bf16x8 a = (k0 < CATD) ? ldb8(irow + k0) : ldb8(hrow + (k0 - CATD));
#pragma unroll
    for (int g = 0; g < 4; ++g) {
      const bf16_t* bp = wbase + (long)g * Hn * KD + k0;
      bf16x8 b0 = ldb8(bp);
      bf16x8 b1 = ldb8(bp + (long)16 * KD);
      acc[g][0] = mfma16(a, b0, acc[g][0]);
      acc[g][1] = mfma16(a, b1, acc[g][1]);
    }
  }
#pragma unroll
  for (int s = 0; s < 2; ++s) {
    int j = n0 + s * 16 + l15;
#pragma unroll
    for (int r = 0; r < 4; ++r) {
      int m = m0 + q * 4 + r;
      float Gi = acc[0][s][r] + bias[j];
      float Gf = acc[1][s][r] + bias[Hn + j];
      float Gg = acc[2][s][r] + bias[2 * Hn + j];
      float Go = acc[3][s][r] + bias[3 * Hn + j];
      float ig = sigf(Gi), fg = sigf(Gf);
      float gg = tanhf(Gg), og = sigf(Go);
      long idx = (long)m * Hn + j;
      float cp = c[idx];
      float cn = fg * cp + ig * gg;
      float hn = og * tanhf(cn);
      c[idx] = cn;
      h_out[idx] = (bf16_t)hn;
    }
  }
}

// ---------------- pooled finalize (/len) + lengths output ----------------
__global__ void k_pool_fin(const float* __restrict__ pooled, const int* __restrict__ lens,
                           bf16_t* __restrict__ pb, float* __restrict__ out_len) {
  int i = blockIdx.x * blockDim.x + threadIdx.x;
  if (i < Bn * 2 * Hn) {
    int m = i >> 11;
    pb[i] = (bf16_t)(pooled[i] / (float)lens[m]);
  }
  if (i < Bn) out_len[i] = (float)lens[i];
}

// ---------------- z = eps * exp(0.5 lv) + mu ----------------
// eps = jax.random.normal(key(42), (256,512), float32), MODERN JAX
// (threefry_partitionable=True default), bit_width=32 path:
//   counts = iota_2x32_shape: per element i, x0 = hi32(i)=0, x1 = lo32(i)=i
//   (o1,o2) = threefry2x32(key=(0,42), x0, x1)  [20 rounds]
//   bits = convert_element_type(o1 ^ o2, uint32)   <-- XOR FOLD, not truncation
// then f32 uniform: (bits>>9)|0x3F800000, -1, *2 + nextafter(-1,0), clamp;
// eps = sqrt(2)*erfinv(u)  [XLA Giles polynomial].
DEV unsigned rotl32(unsigned v, int s) { return (v << s) | (v >> (32 - s)); }

#define TF_R4(r0, r1, r2, r3)                       \
  x0 += x1; x1 = rotl32(x1, r0); x1 ^= x0;          \
  x0 += x1; x1 = rotl32(x1, r1); x1 ^= x0;          \
  x0 += x1; x1 = rotl32(x1, r2); x1 ^= x0;          \
  x0 += x1; x1 = rotl32(x1, r3); x1 ^= x0;

DEV float erfinv_xla(float x) {
  float w = -log1pf(-x * x);
  float p;
  if (w < 5.f) {
    w -= 2.5f;
    p = 2.81022636e-08f;
    p = fmaf(p, w, 3.43273939e-07f);
    p = fmaf(p, w, -3.5233877e-06f);
    p = fmaf(p, w, -4.39150654e-06f);
    p = fmaf(p, w, 0.00021858087f);
    p = fmaf(p, w, -0.00125372503f);
    p = fmaf(p, w, -0.00417768164f);
    p = fmaf(p, w, 0.246640727f);
    p = fmaf(p, w, 1.50140941f);
  } else {
    w = sqrtf(w) - 3.f;
    p = -0.000200214257f;
    p = fmaf(p, w, 0.000100950558f);
    p = fmaf(p, w, 0.00134934322f);
    p = fmaf(p, w, -0.00367342844f);
    p = fmaf(p, w, 0.00573950773f);
    p = fmaf(p, w, -0.0076224613f);
    p = fmaf(p, w, 0.00943887047f);
    p = fmaf(p, w, 1.00167406f);
    p = fmaf(p, w, 2.83297682f);
  }
  return p * x;
}

__global__ void k_z(const float* __restrict__ mu, const float* __restrict__ lv,
                    float* __restrict__ zf, bf16_t* __restrict__ zb) {
  int i = blockIdx.x * blockDim.x + threadIdx.x;  // 0..131071
  const unsigned ks0 = 0u, ks1 = 42u, ks2 = 0x1BD11BDAu ^ ks0 ^ ks1;
  unsigned x0 = 0u + ks0;            // counter hi word (0 for size < 2^32)
  unsigned x1 = (unsigned)i + ks1;   // counter lo word
  TF_R4(13, 15, 26, 6);  x0 += ks1; x1 += ks2 + 1u;
  TF_R4(17, 29, 16, 24); x0 += ks2; x1 += ks0 + 2u;
  TF_R4(13, 15, 26, 6);  x0 += ks0; x1 += ks1 + 3u;
  TF_R4(17, 29, 16, 24); x0 += ks1; x1 += ks2 + 4u;
  TF_R4(13, 15, 26, 6);  x0 += ks2; x1 += ks0 + 5u;
  unsigned bits = x0 ^ x1;  // partitionable bit_width<=32: XOR fold of o1,o2
  float f = __uint_as_float((bits >> 9) | 0x3F800000u) - 1.0f;
  float u = f * 2.0f + (-0.99999994f);
  u = fmaxf(u, -0.99999994f);
  float e = 1.41421356f * erfinv_xla(u);
  float zv = e * expf(0.5f * lv[i]) + mu[i];
  zf[i] = zv;
  zb[i] = (bf16_t)zv;
}

// ---------------- host ----------------
extern "C" void kernel_launch(void* const* d_in, const int* in_sizes, int n_in,
                              void* d_out, int out_size, void* d_ws, size_t ws_size,
                              hipStream_t stream) {
  const float* x     = (const float*)d_in[0];
  const int*   lens  = (const int*)d_in[1];
  const float* ln_w  = (const float*)d_in[2];
  const float* ln_b  = (const float*)d_in[3];
  const float* enc_w = (const float*)d_in[4];
  const float* enc_b = (const float*)d_in[5];
  const float* Wih_f = (const float*)d_in[6];
  const float* Whh_f = (const float*)d_in[7];
  const float* bih_f = (const float*)d_in[8];
  const float* bhh_f = (const float*)d_in[9];
  const float* Wih_b = (const float*)d_in[10];
  const float* Whh_b = (const float*)d_in[11];
  const float* bih_b = (const float*)d_in[12];
  const float* bhh_b = (const float*)d_in[13];
  const float* mu1_w = (const float*)d_in[14];
  const float* mu1_b = (const float*)d_in[15];
  const float* mu2_w = (const float*)d_in[16];
  const float* mu2_b = (const float*)d_in[17];
  const float* lv1_w = (const float*)d_in[18];
  const float* lv1_b = (const float*)d_in[19];
  const float* lv2_w = (const float*)d_in[20];
  const float* lv2_b = (const float*)d_in[21];
  const float* dz_w  = (const float*)d_in[22];
  const float* dz_b  = (const float*)d_in[23];
  const float* p1_w  = (const float*)d_in[24];
  const float* p1_b  = (const float*)d_in[25];
  const float* p2_w  = (const float*)d_in[26];
  const float* p2_b  = (const float*)d_in[27];
  const float* dWih  = (const float*)d_in[28];
  const float* dWhh  = (const float*)d_in[29];
  const float* dbih  = (const float*)d_in[30];
  const float* dbhh  = (const float*)d_in[31];
  const float* l1_w  = (const float*)d_in[32];
  const float* l1_b  = (const float*)d_in[33];
  const float* l2_w  = (const float*)d_in[34];
  const float* l2_b  = (const float*)d_in[35];

  float* out0    = (float*)d_out;
  float* out_dec = out0 + (long)Bn * Ln * Dn;
  float* out_len = out_dec + (long)Bn * Ln * Dn;
  float* out_mu  = out_len + Bn;
  float* out_lv  = out_mu + (long)Bn * Zn;
  float* out_z   = out_lv + (long)Bn * Zn;

  char* wp = (char*)d_ws;
  auto alloc = [&](size_t bytes) -> void* {
    void* r = (void*)wp;
    wp += (bytes + 255) & ~(size_t)255;
    return r;
  };

  bf16_t* xn      = (bf16_t*)alloc((size_t)Bn * Ln * Dn * 2);
  bf16_t* xs      = (bf16_t*)alloc((size_t)Ln * Bn * Zn * 2);
  bf16_t* encw    = (bf16_t*)alloc((size_t)Zn * Dn * 2);
  bf16_t* Wcf     = (bf16_t*)alloc((size_t)4 * Hn * KE * 2);
  bf16_t* Wcb     = (bf16_t*)alloc((size_t)4 * Hn * KE * 2);
  bf16_t* Wcd     = (bf16_t*)alloc((size_t)4 * Hn * KD * 2);
  float*  biasf   = (float*)alloc((size_t)4 * Hn * 4);
  float*  biasb   = (float*)alloc((size_t)4 * Hn * 4);
  float*  biasd   = (float*)alloc((size_t)4 * Hn * 4);
  bf16_t* mu1b    = (bf16_t*)alloc((size_t)Hn * 2 * Hn * 2);
  bf16_t* lv1b    = (bf16_t*)alloc((size_t)Hn * 2 * Hn * 2);
  bf16_t* mu2b    = (bf16_t*)alloc((size_t)Zn * Hn * 2);
  bf16_t* lv2b    = (bf16_t*)alloc((size_t)Zn * Hn * 2);
  bf16_t* dzb     = (bf16_t*)alloc((size_t)Zn * Zn * 2);
  bf16_t* p1b     = (bf16_t*)alloc((size_t)Zn * Zn * 2);
  bf16_t* p2b     = (bf16_t*)alloc((size_t)Dn * Zn * 2);
  bf16_t* l1b     = (bf16_t*)alloc((size_t)Zn * Hn * 2);
  bf16_t* l2b     = (bf16_t*)alloc((size_t)Dn * Zn * 2);
  bf16_t* hf0     = (bf16_t*)alloc((size_t)Bn * Hn * 2);
  bf16_t* hf1     = (bf16_t*)alloc((size_t)Bn * Hn * 2);
  bf16_t* hb0     = (bf16_t*)alloc((size_t)Bn * Hn * 2);
  bf16_t* hb1     = (bf16_t*)alloc((size_t)Bn * Hn * 2);
  bf16_t* hd0     = (bf16_t*)alloc((size_t)Bn * Hn * 2);
  bf16_t* hd1     = (bf16_t*)alloc((size_t)Bn * Hn * 2);
  float*  cf      = (float*)alloc((size_t)Bn * Hn * 4);
  float*  cb      = (float*)alloc((size_t)Bn * Hn * 4);
  float*  cd      = (float*)alloc((size_t)Bn * Hn * 4);
  float*  pooled  = (float*)alloc((size_t)Bn * 2 * Hn * 4);
  bf16_t* pooledb = (bf16_t*)alloc((size_t)Bn * 2 * Hn * 2);
  bf16_t* mu_h    = (bf16_t*)alloc((size_t)Bn * Hn * 2);
  bf16_t* lv_h    = (bf16_t*)alloc((size_t)Bn * Hn * 2);
  bf16_t* zb      = (bf16_t*)alloc((size_t)Bn * Zn * 2);
  bf16_t* inp     = (bf16_t*)alloc((size_t)Bn * CATD * 2);
  bf16_t* t1      = (bf16_t*)alloc((size_t)Bn * Zn * 2);

  // zero-init state (d_ws is poisoned 0xAA before every call)
  hipMemsetAsync(pooled, 0, (size_t)Bn * 2 * Hn * 4, stream);
  hipMemsetAsync(cf, 0, (size_t)Bn * Hn * 4, stream);
  hipMemsetAsync(cb, 0, (size_t)Bn * Hn * 4, stream);
  hipMemsetAsync(cd, 0, (size_t)Bn * Hn * 4, stream);
  hipMemsetAsync(hf0, 0, (size_t)Bn * Hn * 2, stream);
  hipMemsetAsync(hb0, 0, (size_t)Bn * Hn * 2, stream);
  hipMemsetAsync(hd0, 0, (size_t)Bn * Hn * 2, stream);

  auto cg = [](long n) { long g = (n + 255) >> 8; return (int)(g > 2048 ? 2048 : g); };

  // weight prep (bf16 casts / packs / bias sums)
  k_cast<<<cg(Zn * Dn), 256, 0, stream>>>(enc_w, encw, Zn * Dn);
  k_pack2<<<2048, 256, 0, stream>>>(Wih_f, Zn, Whh_f, Hn, Wcf, (long)4 * Hn * KE);
  k_pack2<<<2048, 256, 0, stream>>>(Wih_b, Zn, Whh_b, Hn, Wcb, (long)4 * Hn * KE);
  k_pack2<<<2048, 256, 0, stream>>>(dWih, CATD, dWhh, Hn, Wcd, (long)4 * Hn * KD);
  k_addbias<<<16, 256, 0, stream>>>(bih_f, bhh_f, biasf, 4 * Hn);
  k_addbias<<<16, 256, 0, stream>>>(bih_b, bhh_b, biasb, 4 * Hn);
  k_addbias<<<16, 256, 0, stream>>>(dbih, dbhh, biasd, 4 * Hn);
  k_cast<<<cg((long)Hn * 2 * Hn), 256, 0, stream>>>(mu1_w, mu1b, Hn * 2 * Hn);
  k_cast<<<cg((long)Hn * 2 * Hn), 256, 0, stream>>>(lv1_w, lv1b, Hn * 2 * Hn);
  k_cast<<<cg((long)Zn * Hn), 256, 0, stream>>>(mu2_w, mu2b, Zn * Hn);
  k_cast<<<cg((long)Zn * Hn), 256, 0, stream>>>(lv2_w, lv2b, Zn * Hn);
  k_cast<<<cg((long)Zn * Zn), 256, 0, stream>>>(dz_w, dzb, Zn * Zn);
  k_cast<<<cg((long)Zn * Zn), 256, 0, stream>>>(p1_w, p1b, Zn * Zn);
  k_cast<<<cg((long)Dn * Zn), 256, 0, stream>>>(p2_w, p2b, Dn * Zn);
  k_cast<<<cg((long)Zn * Hn), 256, 0, stream>>>(l1_w, l1b, Zn * Hn);
  k_cast<<<cg((long)Dn * Zn), 256, 0, stream>>>(l2_w, l2b, Dn * Zn);

  // layernorm + x passthrough
  k_layernorm<<<256, 256, 0, stream>>>(x, ln_w, ln_b, out0, xn);

  // encoder: xs[l][b][:] = relu(xn @ enc_w^T + enc_b)
  k_gemm<1, true><<<dim3(480, 8), 256, 0, stream>>>(xn, Dn, encw, Dn, enc_b,
                                                    nullptr, 0, xs, Zn, Dn);

  // BiLSTM over 120 steps
  for (int t = 0; t < Ln; ++t) {
    const bf16_t* hfi = (t & 1) ? hf1 : hf0; bf16_t* hfo = (t & 1) ? hf0 : hf1;
    const bf16_t* hbi = (t & 1) ? hb1 : hb0; bf16_t* hbo = (t & 1) ? hb0 : hb1;
    k_enc_step<<<dim3(8, 16, 2), 256, 0, stream>>>(xs, t, Wcf, Wcb, biasf, biasb, lens,
                                                   hfi, hfo, hbi, hbo, cf, cb, pooled);
  }

  k_pool_fin<<<(Bn * 2 * Hn + 255) / 256, 256, 0, stream>>>(pooled, lens, pooledb, out_len);

  // mu / log_var heads
  k_gemm<1, false><<<dim3(4, 16), 256, 0, stream>>>(pooledb, 2 * Hn, mu1b, 2 * Hn, mu1_b,
                                                    nullptr, 0, mu_h, Hn, 2 * Hn);
  k_gemm<1, false><<<dim3(4, 16), 256, 0, stream>>>(pooledb, 2 * Hn, lv1b, 2 * Hn, lv1_b,
                                                    nullptr, 0, lv_h, Hn, 2 * Hn);
  k_gemm<0, false><<<dim3(4, 8), 256, 0, stream>>>(mu_h, Hn, mu2b, Hn, mu2_b,
                                                   out_mu, Zn, nullptr, 0, Hn);
  k_gemm<0, false><<<dim3(4, 8), 256, 0, stream>>>(lv_h, Hn, lv2b, Hn, lv2_b,
                                                   out_lv, Zn, nullptr, 0, Hn);

  // z = eps * exp(0.5 lv) + mu  (jax threefry partitionable f32, XOR fold)
  k_z<<<512, 256, 0, stream>>>(out_mu, out_lv, out_z, zb);

  // decoder init: xz -> inp[:,0:512]; pose0 -> inp[:,512:704]
  k_gemm<1, false><<<dim3(4, 8), 256, 0, stream>>>(zb, Zn, dzb, Zn, dz_b,
                                                   nullptr, 0, inp, CATD, Zn);
  k_gemm<1, false><<<dim3(4, 8), 256, 0, stream>>>(inp, CATD, p1b, Zn, p1_b,
                                                   nullptr, 0, t1, Zn, Zn);
  k_gemm<0, false><<<dim3(4, 3), 256, 0, stream>>>(t1, Zn, p2b, Zn, p2_b,
                                                   nullptr, 0, inp + Zn, CATD, Zn);

  // decoder LSTM with pose feedback
  for (int t = 0; t < Ln; ++t) {
    const bf16_t* hi = (t & 1) ? hd1 : hd0; bf16_t* ho = (t & 1) ? hd0 : hd1;
    k_dec_step<<<dim3(8, 16), 256, 0, stream>>>(inp, hi, ho, Wcd, biasd, cd);
    k_gemm<1, false><<<dim3(4, 8), 256, 0, stream>>>(ho, Hn, l1b, Hn, l1_b,
                                                     nullptr, 0, t1, Zn, Hn);
    k_gemm<0, false><<<dim3(4, 3), 256, 0, stream>>>(t1, Zn, l2b, Zn, l2_b,
                                                     out_dec + (long)t * Dn, (long)Ln * Dn,
                                                     inp + Zn, CATD, Zn);
  }
}